// Round 10
// baseline (65.109 us; speedup 1.0000x reference)
//
#include <hip/hip_runtime.h>
#include <math.h>

#define BIG_NEG (-1.0e9f)

constexpr int B = 16, T = 2048, D = 64, C = 32, NF = 16;
constexpr int CS_STRIDE = 2052;   // T+1 padded to multiple of 4 (16B alignment)

typedef float f32x4 __attribute__((ext_vector_type(4)));

// ws layout (floats):
//   [64]                log_norm (ln)
//   [128 .. 128+K*C)    llp_eff[k][c] = (k+1)*(plr[c]+ln) - exp(plr[c]) - lgamma(k+2)
//   [4096 .. )          cs, layout (b,c,CS_STRIDE)
//
// em_core[t,c] = -0.5 * sum_d (f-m)^2 * iv   (log_norm folded into llp_eff;
// cc is part of the (f-m)^2 expansion). span_valid = cs[e]-cs[s]+llp_eff.
// span_masked = BIG_NEG + llp_orig = (BIG_NEG - (k+1)*ln) + llp_eff.

// ---------------------------------------------------------------------------
// fused kernel: blocks 0..511 = emission+scan per (b,c); block 512 = trans;
// block 513 = llp_eff + log_norm + init_lp.
// ---------------------------------------------------------------------------
__global__ __launch_bounds__(256) void fused_kernel(
    const float* __restrict__ feat,    // (B,T,D)
    const float* __restrict__ P,       // (D,NF)
    const float* __restrict__ TL,      // (C,D)
    const float* __restrict__ TR,      // (C,D)
    const float* __restrict__ STD,     // (D,)
    const float* __restrict__ MEANS,   // (C,D)
    const float* __restrict__ PLR,     // (C,)
    const float* __restrict__ LOGITS,  // (C,)
    float* __restrict__ ws,
    float* __restrict__ cs,            // (B,C,CS_STRIDE)
    float* __restrict__ out_trans,     // (C,C)
    float* __restrict__ out_init,      // (C,)
    int K)
{
    const int bid = blockIdx.x;
    const int tid = threadIdx.x;

    if (bid < B * C) {
        // ---------------- emission + scan for one (b,c) ----------------
        const int b = bid & 15, c = bid >> 4;
        const int lane = tid & 63, wid = tid >> 6;

        float em8[8];
#pragma unroll
        for (int j = 0; j < 8; ++j) em8[j] = 0.f;

        const float* frow = feat + ((size_t)b * T + (size_t)tid * 8) * D;
        const float* mrow = MEANS + c * D;

#pragma unroll
        for (int qc = 0; qc < 4; ++qc) {          // d in chunks of 16
            float4 m[4], v[4];
#pragma unroll
            for (int u = 0; u < 4; ++u) {
                m[u] = *(const float4*)(mrow + qc * 16 + u * 4);
                const float4 s = *(const float4*)(STD + qc * 16 + u * 4);
                v[u].x = 1.f / (s.x * s.x);
                v[u].y = 1.f / (s.y * s.y);
                v[u].z = 1.f / (s.z * s.z);
                v[u].w = 1.f / (s.w * s.w);
            }
#pragma unroll
            for (int j = 0; j < 8; ++j) {
                const float* fp = frow + (size_t)j * D + qc * 16;
                float acc = em8[j];
#pragma unroll
                for (int u = 0; u < 4; ++u) {
                    const float4 f = *(const float4*)(fp + u * 4);
                    float dx;
                    dx = f.x - m[u].x; acc = fmaf(dx * v[u].x, dx, acc);
                    dx = f.y - m[u].y; acc = fmaf(dx * v[u].y, dx, acc);
                    dx = f.z - m[u].z; acc = fmaf(dx * v[u].z, dx, acc);
                    dx = f.w - m[u].w; acc = fmaf(dx * v[u].w, dx, acc);
                }
                em8[j] = acc;
            }
        }

        // per-thread inclusive prefix of em_core = -0.5*em8
        float loc[8], run = 0.f;
#pragma unroll
        for (int j = 0; j < 8; ++j) { run += -0.5f * em8[j]; loc[j] = run; }

        // wave64 inclusive scan of per-thread totals
        float sc = run;
#pragma unroll
        for (int off = 1; off < 64; off <<= 1) {
            float vv = __shfl_up(sc, off, 64);
            if (lane >= off) sc += vv;
        }
        __shared__ float wsum[4];
        if (lane == 63) wsum[wid] = sc;
        __syncthreads();
        float wpre = 0.f;
#pragma unroll
        for (int w = 0; w < 3; ++w) wpre += (w < wid) ? wsum[w] : 0.f;
        const float excl = wpre + sc - run;   // exclusive prefix at t0=tid*8

        float* cbase = cs + (size_t)(b * C + c) * CS_STRIDE;
        f32x4 o0 = {excl, excl + loc[0], excl + loc[1], excl + loc[2]};
        f32x4 o1 = {excl + loc[3], excl + loc[4], excl + loc[5], excl + loc[6]};
        *(f32x4*)(cbase + tid * 8) = o0;
        *(f32x4*)(cbase + tid * 8 + 4) = o1;
        if (tid == 255) cbase[T] = excl + loc[7];

    } else if (bid == B * C) {
        // ---------------- transition log-softmax ----------------
        __shared__ float left[C][NF], right[C][NF], M[C][C + 1], lse[C];
        for (int e = tid; e < C * NF; e += 256) {
            int cc = e >> 4, f = e & (NF - 1);
            float aL = 0.f, aR = 0.f;
            for (int d = 0; d < D; ++d) {
                float p = P[d * NF + f];
                aL = fmaf(TL[cc * D + d], p, aL);
                aR = fmaf(TR[cc * D + d], p, aR);
            }
            left[cc][f] = aL; right[cc][f] = aR;
        }
        __syncthreads();
        for (int e = tid; e < C * C; e += 256) {
            int i = e >> 5, j = e & 31;
            float acc = 0.f;
            for (int f = 0; f < NF; ++f) acc = fmaf(right[i][f], left[j][f], acc);
            M[i][j] = acc;
        }
        __syncthreads();
        if (tid < C) {
            float mx = -INFINITY;
            for (int i = 0; i < C; ++i) mx = fmaxf(mx, M[i][tid]);
            float s = 0.f;
            for (int i = 0; i < C; ++i) s += expf(M[i][tid] - mx);
            lse[tid] = logf(s) + mx;
        }
        __syncthreads();
        for (int e = tid; e < C * C; e += 256)
            out_trans[e] = M[e >> 5][e & 31] - lse[e & 31];

    } else {
        // ---------------- llp_eff + log_norm + init_lp ----------------
        __shared__ float lgam[32];
        __shared__ float sln;
        if (tid < 32) {
            // lane k: inclusive scan of log(j+1) -> log((k+1)!) = lgamma(k+2)
            float x = (tid >= 1) ? logf((float)(tid + 1)) : 0.f;
#pragma unroll
            for (int off = 1; off < 32; off <<= 1) {
                float vv = __shfl_up(x, off, 64);
                if (tid >= off) x += vv;
            }
            lgam[tid] = x;
        } else if (tid >= 64 && tid < 128) {
            // wave 1: log_norm = -sum(log(std)) - 0.5*D*log(2*pi)
            const int l = tid - 64;
            float lg = logf(STD[l]);
#pragma unroll
            for (int off = 1; off < 64; off <<= 1) lg += __shfl_xor(lg, off, 64);
            if (l == 0) {
                float ln = -lg - 58.81206612510332f;
                sln = ln;
                ws[64] = ln;
            }
        } else if (tid >= 128 && tid < 160) {
            // half of wave 2: init_lp via 32-lane butterflies
            const int l = tid - 128;
            float vv = LOGITS[l];
            float mx = vv;
#pragma unroll
            for (int off = 1; off < 32; off <<= 1)
                mx = fmaxf(mx, __shfl_xor(mx, off, 64));
            float s = expf(vv - mx);
#pragma unroll
            for (int off = 1; off < 32; off <<= 1) s += __shfl_xor(s, off, 64);
            out_init[l] = vv - mx - logf(s);
        }
        __syncthreads();
        const float ln = sln;
        for (int e = tid; e < K * C; e += 256) {
            int k = e >> 5, cc = e & 31;
            float plr = PLR[cc];
            ws[128 + e] = (float)(k + 1) * (plr + ln) - expf(plr) - lgam[k];
        }
    }
}

// ---------------------------------------------------------------------------
// span: block = (b, t-chunk of 64); stages cs rows [t0-KT, t0+64] + llp_eff
// in LDS; k-outer contiguous panel writes. Masked branch corrected by
// -(k+1)*ln to undo the log_norm fold. blockIdx = chunk*16 + b (XCD = b%8).
// ---------------------------------------------------------------------------
template<int KT>
__global__ __launch_bounds__(256) void span_kernel_t(
    const float* __restrict__ cs,      // (B,C,CS_STRIDE)
    const float* __restrict__ ws,      // ws[64]=ln, ws+128=llp_eff
    float* __restrict__ out)           // (B,KT,T,C)
{
    constexpr int ROWS = 64 + KT + 1;  // rows t0-KT .. t0+64
    __shared__ float slds[ROWS * C];   // [row][c]
    __shared__ float sllp[KT * C];

    const int tid = threadIdx.x;
    const int b = blockIdx.x & 15;
    const int t0 = (blockIdx.x >> 4) << 6;   // chunk * 64

    const float* csb = cs + (size_t)b * C * CS_STRIDE;
    for (int i = tid; i < ROWS * C; i += 256) {
        const int c = i / ROWS;
        const int r = i - c * ROWS;
        int t = t0 - KT + r;
        if (t < 0) t = 0;
        slds[r * C + c] = csb[(size_t)c * CS_STRIDE + t];
    }
    const float* llp = ws + 128;
    for (int i = tid; i < KT * C; i += 256) sllp[i] = llp[i];
    __syncthreads();

    const float ln = ws[64];

    const int c4 = (tid & 7) << 2;
    const int tb = tid >> 3;                 // 0..31
    const int ja = tb + KT;                  // LDS row of cs[t0+tb]
    const int jb = ja + 32;                  // LDS row of cs[t0+32+tb]
    const int ta = t0 + tb;
    const int tbig = t0 + 32 + tb;

    const f32x4 ea = *(const f32x4*)&slds[(ja + 1) * C + c4];
    const f32x4 eb = *(const f32x4*)&slds[(jb + 1) * C + c4];

    float* ob = out + ((size_t)(b * KT) * T + t0) * C + c4;

#pragma unroll
    for (int k = 0; k < KT; ++k) {
        const f32x4 lv = *(const f32x4*)&sllp[k * C + c4];
        const f32x4 sa = *(const f32x4*)&slds[(ja - k) * C + c4];
        const f32x4 sb = *(const f32x4*)&slds[(jb - k) * C + c4];
        const float mk = BIG_NEG - (float)(k + 1) * ln;   // undo fold for mask
        f32x4 ra = ea - sa + lv;
        f32x4 rb = eb - sb + lv;
        if (ta < k) ra = mk + lv;
        if (tbig < k) rb = mk + lv;
        float* op = ob + (size_t)k * T * C;
        *(f32x4*)(op + tb * C) = ra;
        *(f32x4*)(op + (32 + tb) * C) = rb;
    }
}

// runtime-K fallback (dynamic LDS)
__global__ __launch_bounds__(256) void span_kernel_rt(
    const float* __restrict__ cs,
    const float* __restrict__ ws,
    float* __restrict__ out,
    int K)
{
    extern __shared__ float dyn[];
    float* slds = dyn;                 // (64+K+1) * C
    float* sllp = dyn + (64 + K + 1) * C;

    const int tid = threadIdx.x;
    const int b = blockIdx.x & 15;
    const int t0 = (blockIdx.x >> 4) << 6;
    const int ROWS = 64 + K + 1;

    const float* csb = cs + (size_t)b * C * CS_STRIDE;
    for (int i = tid; i < ROWS * C; i += 256) {
        const int c = i / ROWS;
        const int r = i - c * ROWS;
        int t = t0 - K + r;
        if (t < 0) t = 0;
        slds[r * C + c] = csb[(size_t)c * CS_STRIDE + t];
    }
    const float* llp = ws + 128;
    for (int i = tid; i < K * C; i += 256) sllp[i] = llp[i];
    __syncthreads();

    const float ln = ws[64];

    const int c4 = (tid & 7) << 2;
    const int tb = tid >> 3;
    const int ja = tb + K;
    const int jb = ja + 32;
    const int ta = t0 + tb;
    const int tbig = t0 + 32 + tb;

    const f32x4 ea = *(const f32x4*)&slds[(ja + 1) * C + c4];
    const f32x4 eb = *(const f32x4*)&slds[(jb + 1) * C + c4];

    float* ob = out + ((size_t)(b * K) * T + t0) * C + c4;

    for (int k = 0; k < K; ++k) {
        const f32x4 lv = *(const f32x4*)&sllp[k * C + c4];
        const f32x4 sa = *(const f32x4*)&slds[(ja - k) * C + c4];
        const f32x4 sb = *(const f32x4*)&slds[(jb - k) * C + c4];
        const float mk = BIG_NEG - (float)(k + 1) * ln;
        f32x4 ra = ea - sa + lv;
        f32x4 rb = eb - sb + lv;
        if (ta < k) ra = mk + lv;
        if (tbig < k) rb = mk + lv;
        float* op = ob + (size_t)k * T * C;
        *(f32x4*)(op + tb * C) = ra;
        *(f32x4*)(op + (32 + tb) * C) = rb;
    }
}

// ---------------------------------------------------------------------------
extern "C" void kernel_launch(void* const* d_in, const int* in_sizes, int n_in,
                              void* d_out, int out_size, void* d_ws, size_t ws_size,
                              hipStream_t stream) {
    const float* feat   = (const float*)d_in[0];
    const float* P      = (const float*)d_in[1];
    const float* TL     = (const float*)d_in[2];
    const float* TR     = (const float*)d_in[3];
    const float* MEANS  = (const float*)d_in[4];
    const float* STDV   = (const float*)d_in[5];
    const float* PLR    = (const float*)d_in[6];
    const float* LOGITS = (const float*)d_in[7];

    const int K = (out_size - (C * C + C)) / (B * T * C);

    float* ws = (float*)d_ws;
    float* cs = ws + 4096;

    float* out       = (float*)d_out;
    float* out_trans = out + (size_t)B * K * T * C;
    float* out_init  = out_trans + C * C;

    fused_kernel<<<B * C + 2, 256, 0, stream>>>(feat, P, TL, TR, STDV, MEANS,
                                                PLR, LOGITS, ws, cs,
                                                out_trans, out_init, K);

    const int nblk = B * (T / 64);     // 512 blocks: (b, 32 chunks)
    if (K == 20) {
        span_kernel_t<20><<<nblk, 256, 0, stream>>>(cs, ws, out);
    } else if (K == 16) {
        span_kernel_t<16><<<nblk, 256, 0, stream>>>(cs, ws, out);
    } else if (K == 24) {
        span_kernel_t<24><<<nblk, 256, 0, stream>>>(cs, ws, out);
    } else {
        const size_t smem = (size_t)((64 + K + 1) + K) * C * sizeof(float);
        span_kernel_rt<<<nblk, 256, smem, stream>>>(cs, ws, out, K);
    }
}

// Round 11
// 36.869 us; speedup vs baseline: 1.7659x; 1.7659x over previous
//
#include <hip/hip_runtime.h>
#include <math.h>

#define BIG_NEG (-1.0e9f)

constexpr int B = 16, T = 2048, D = 64, C = 32, NF = 16;
constexpr int CS_STRIDE = 2052;   // T+1 padded to multiple of 4 (16B alignment)

typedef float f32x4 __attribute__((ext_vector_type(4)));

// ws layout (floats):
//   [0..31]             lncc[c] = ln + cc[c]        (mask correction)
//   [128 .. 128+K*C)    llp_eff[k][c] = llp_orig + (k+1)*(ln + cc[c])
//   [4096 .. )          cs  (B,C,CS_STRIDE)
//   [4096+B*C*CS_STRIDE ..) emT (B,C,T)
//
// em_core[t,c] = xm - 0.5*xx   (ln and cc = -0.5*mm folded into llp_eff)
// span_valid  = cs_diff + llp_eff
// span_masked = (BIG_NEG - (k+1)*lncc[c]) + llp_eff

// ---------------------------------------------------------------------------
// fused kernel A:
//   blocks 0..511 : emission for (b, 64-t chunk) — LDS-staged, coalesced
//   block  512    : transition log-softmax
//   block  513    : llp_eff + lncc + init_lp
// ---------------------------------------------------------------------------
__global__ __launch_bounds__(256) void fused_kernel(
    const float* __restrict__ feat,    // (B,T,D)
    const float* __restrict__ P,       // (D,NF)
    const float* __restrict__ TL,      // (C,D)
    const float* __restrict__ TR,      // (C,D)
    const float* __restrict__ STD,     // (D,)
    const float* __restrict__ MEANS,   // (C,D)
    const float* __restrict__ PLR,     // (C,)
    const float* __restrict__ LOGITS,  // (C,)
    float* __restrict__ ws,
    float* __restrict__ emT,           // (B,C,T)
    float* __restrict__ out_trans,     // (C,C)
    float* __restrict__ out_init,      // (C,)
    int K)
{
    const int bid = blockIdx.x;
    const int tid = threadIdx.x;

    if (bid < 512) {
        // ---------------- emission for (b, t-chunk of 64) ----------------
        const int b  = bid & 15;          // XCD = b%8
        const int t0 = (bid >> 4) << 6;

        __shared__ float f_lds[64 * 64];  // XOR-swizzled
        __shared__ float wm_lds[32 * 68]; // wm[c][d], stride 68
        __shared__ float iv_lds[64];

        // stage iv (threads 0..15)
        if (tid < 16) {
            const f32x4 s = *(const f32x4*)(STD + tid * 4);
            f32x4 v = {1.f / (s.x * s.x), 1.f / (s.y * s.y),
                       1.f / (s.z * s.z), 1.f / (s.w * s.w)};
            *(f32x4*)(iv_lds + tid * 4) = v;
        }
        // stage wm = MEANS * iv  (2048 floats, 2 x f32x4 per thread)
#pragma unroll
        for (int it = 0; it < 2; ++it) {
            const int idx = tid * 4 + it * 1024;
            const int c = idx >> 6, d = idx & 63;
            const f32x4 m = *(const f32x4*)(MEANS + idx);
            const f32x4 s = *(const f32x4*)(STD + d);
            f32x4 w = {m.x / (s.x * s.x), m.y / (s.y * s.y),
                       m.z / (s.z * s.z), m.w / (s.w * s.w)};
            *(f32x4*)(wm_lds + c * 68 + d) = w;
        }
        // stage feat tile (4096 floats) — coalesced global, swizzled LDS
        const float* featb = feat + ((size_t)b * T + t0) * D;
#pragma unroll
        for (int it = 0; it < 4; ++it) {
            const int idx = tid * 4 + it * 1024;
            const f32x4 v = *(const f32x4*)(featb + idx);
            const int row = idx >> 6;
            const int col = (idx & 63) ^ (((row >> 2) & 7) << 2);
            *(f32x4*)(f_lds + row * 64 + col) = v;
        }
        __syncthreads();

        // compute: thread (i = t-quad, j = c-pair) -> 4t x 2c register tile
        const int i = tid & 15, j = tid >> 4;
        const int swz = (i & 7) << 2;
        const float* wr0 = wm_lds + (2 * j) * 68;
        const float* wr1 = wr0 + 68;

        float a0[4] = {0.f, 0.f, 0.f, 0.f};
        float a1[4] = {0.f, 0.f, 0.f, 0.f};
        float xx[4] = {0.f, 0.f, 0.f, 0.f};

#pragma unroll
        for (int q = 0; q < 16; ++q) {
            const int dq = q * 4;
            const f32x4 w0  = *(const f32x4*)(wr0 + dq);
            const f32x4 w1  = *(const f32x4*)(wr1 + dq);
            const f32x4 iv4 = *(const f32x4*)(iv_lds + dq);
            const int cswz = dq ^ swz;
#pragma unroll
            for (int tt = 0; tt < 4; ++tt) {
                const f32x4 f = *(const f32x4*)(f_lds + (4 * i + tt) * 64 + cswz);
                a0[tt] = fmaf(f.x, w0.x, a0[tt]); a0[tt] = fmaf(f.y, w0.y, a0[tt]);
                a0[tt] = fmaf(f.z, w0.z, a0[tt]); a0[tt] = fmaf(f.w, w0.w, a0[tt]);
                a1[tt] = fmaf(f.x, w1.x, a1[tt]); a1[tt] = fmaf(f.y, w1.y, a1[tt]);
                a1[tt] = fmaf(f.z, w1.z, a1[tt]); a1[tt] = fmaf(f.w, w1.w, a1[tt]);
                xx[tt] = fmaf(f.x * iv4.x, f.x, xx[tt]);
                xx[tt] = fmaf(f.y * iv4.y, f.y, xx[tt]);
                xx[tt] = fmaf(f.z * iv4.z, f.z, xx[tt]);
                xx[tt] = fmaf(f.w * iv4.w, f.w, xx[tt]);
            }
        }

        float* e0 = emT + ((size_t)(b * C + 2 * j)) * T + t0 + 4 * i;
        f32x4 o0 = {a0[0] - 0.5f * xx[0], a0[1] - 0.5f * xx[1],
                    a0[2] - 0.5f * xx[2], a0[3] - 0.5f * xx[3]};
        f32x4 o1 = {a1[0] - 0.5f * xx[0], a1[1] - 0.5f * xx[1],
                    a1[2] - 0.5f * xx[2], a1[3] - 0.5f * xx[3]};
        *(f32x4*)e0 = o0;
        *(f32x4*)(e0 + T) = o1;

    } else if (bid == 512) {
        // ---------------- transition log-softmax ----------------
        __shared__ float left[C][NF], right[C][NF], M[C][C + 1], lse[C];
        for (int e = tid; e < C * NF; e += 256) {
            int cc = e >> 4, f = e & (NF - 1);
            float aL = 0.f, aR = 0.f;
            for (int d = 0; d < D; ++d) {
                float p = P[d * NF + f];
                aL = fmaf(TL[cc * D + d], p, aL);
                aR = fmaf(TR[cc * D + d], p, aR);
            }
            left[cc][f] = aL; right[cc][f] = aR;
        }
        __syncthreads();
        for (int e = tid; e < C * C; e += 256) {
            int i = e >> 5, jj = e & 31;
            float acc = 0.f;
            for (int f = 0; f < NF; ++f) acc = fmaf(right[i][f], left[jj][f], acc);
            M[i][jj] = acc;
        }
        __syncthreads();
        if (tid < C) {
            float mx = -INFINITY;
            for (int i = 0; i < C; ++i) mx = fmaxf(mx, M[i][tid]);
            float s = 0.f;
            for (int i = 0; i < C; ++i) s += expf(M[i][tid] - mx);
            lse[tid] = logf(s) + mx;
        }
        __syncthreads();
        for (int e = tid; e < C * C; e += 256)
            out_trans[e] = M[e >> 5][e & 31] - lse[e & 31];

    } else {
        // ---------------- llp_eff + lncc + init_lp ----------------
        __shared__ float lgam[32];
        __shared__ float scc[32];
        __shared__ float sln;
        if (tid < 32) {
            // lane k: inclusive scan of log(j+1) -> lgamma(k+2)
            float x = (tid >= 1) ? logf((float)(tid + 1)) : 0.f;
#pragma unroll
            for (int off = 1; off < 32; off <<= 1) {
                float vv = __shfl_up(x, off, 64);
                if (tid >= off) x += vv;
            }
            lgam[tid] = x;
        } else if (tid >= 64 && tid < 128) {
            // wave 1: log_norm = -sum(log(std)) - 0.5*D*log(2*pi)
            const int l = tid - 64;
            float lg = logf(STD[l]);
#pragma unroll
            for (int off = 1; off < 64; off <<= 1) lg += __shfl_xor(lg, off, 64);
            if (l == 0) sln = -lg - 58.81206612510332f;
        } else if (tid >= 128 && tid < 160) {
            // half of wave 2: init_lp via 32-lane butterflies
            const int l = tid - 128;
            float vv = LOGITS[l];
            float mx = vv;
#pragma unroll
            for (int off = 1; off < 32; off <<= 1)
                mx = fmaxf(mx, __shfl_xor(mx, off, 64));
            float s = expf(vv - mx);
#pragma unroll
            for (int off = 1; off < 32; off <<= 1) s += __shfl_xor(s, off, 64);
            out_init[l] = vv - mx - logf(s);
        } else if (tid >= 192 && tid < 224) {
            // wave 3 lanes 0-31: cc[c] = -0.5 * sum_d m^2/std^2
            const int c = tid - 192;
            float acc = 0.f;
#pragma unroll
            for (int dq = 0; dq < 64; dq += 4) {
                const f32x4 m = *(const f32x4*)(MEANS + c * 64 + dq);
                const f32x4 s = *(const f32x4*)(STD + dq);
                acc += (m.x * m.x) / (s.x * s.x) + (m.y * m.y) / (s.y * s.y)
                     + (m.z * m.z) / (s.z * s.z) + (m.w * m.w) / (s.w * s.w);
            }
            scc[c] = -0.5f * acc;
        }
        __syncthreads();
        const float ln = sln;
        if (tid < 32) ws[tid] = ln + scc[tid];   // lncc
        for (int e = tid; e < K * C; e += 256) {
            int k = e >> 5, cc = e & 31;
            float plr = PLR[cc];
            ws[128 + e] = (float)(k + 1) * (plr + ln + scc[cc])
                          - expf(plr) - lgam[k];
        }
    }
}

// ---------------------------------------------------------------------------
// scan: cumsum over T per (b,c); blockIdx = c*16 + b (XCD = b%8).
// reads emT contiguously, writes cs (b,c,t) padded — per-thread aligned f32x4.
// ---------------------------------------------------------------------------
__global__ __launch_bounds__(256) void scan_kernel(
    const float* __restrict__ emT,     // (B,C,T)
    float* __restrict__ cs)            // (B,C,CS_STRIDE)
{
    __shared__ float wsum[4];
    const int tid = threadIdx.x;
    const int b = blockIdx.x & 15, c = blockIdx.x >> 4;
    const int lane = tid & 63, wid = tid >> 6;

    const float* ebase = emT + ((size_t)(b * C + c)) * T + tid * 8;
    const f32x4 v0 = *(const f32x4*)ebase;
    const f32x4 v1 = *(const f32x4*)(ebase + 4);

    float loc[8];
    float run = 0.0f;
    run += v0.x; loc[0] = run;
    run += v0.y; loc[1] = run;
    run += v0.z; loc[2] = run;
    run += v0.w; loc[3] = run;
    run += v1.x; loc[4] = run;
    run += v1.y; loc[5] = run;
    run += v1.z; loc[6] = run;
    run += v1.w; loc[7] = run;

    float sc = run;
#pragma unroll
    for (int off = 1; off < 64; off <<= 1) {
        float v = __shfl_up(sc, off, 64);
        if (lane >= off) sc += v;
    }
    if (lane == 63) wsum[wid] = sc;
    __syncthreads();
    float wpre = 0.0f;
#pragma unroll
    for (int w = 0; w < 3; ++w)
        wpre += (w < wid) ? wsum[w] : 0.0f;

    const float excl = wpre + sc - run;   // exclusive prefix at t0 = tid*8

    float* cbase = cs + (size_t)(b * C + c) * CS_STRIDE;
    f32x4 o0 = {excl, excl + loc[0], excl + loc[1], excl + loc[2]};
    f32x4 o1 = {excl + loc[3], excl + loc[4], excl + loc[5], excl + loc[6]};
    *(f32x4*)(cbase + tid * 8) = o0;
    *(f32x4*)(cbase + tid * 8 + 4) = o1;
    if (tid == 255) cbase[T] = excl + loc[7];   // total
}

// ---------------------------------------------------------------------------
// span: block = (b, t-chunk of 64); LDS-staged cs rows + llp_eff; k-outer
// contiguous panel writes. Masked branch: BIG_NEG - (k+1)*lncc[c] + llp_eff.
// ---------------------------------------------------------------------------
template<int KT>
__global__ __launch_bounds__(256) void span_kernel_t(
    const float* __restrict__ cs,      // (B,C,CS_STRIDE)
    const float* __restrict__ ws,      // [0..31]=lncc, +128=llp_eff
    float* __restrict__ out)           // (B,KT,T,C)
{
    constexpr int ROWS = 64 + KT + 1;
    __shared__ float slds[ROWS * C];   // [row][c]
    __shared__ float sllp[KT * C];
    __shared__ float slncc[C];

    const int tid = threadIdx.x;
    const int b = blockIdx.x & 15;
    const int t0 = (blockIdx.x >> 4) << 6;

    const float* csb = cs + (size_t)b * C * CS_STRIDE;
    for (int i = tid; i < ROWS * C; i += 256) {
        const int c = i / ROWS;
        const int r = i - c * ROWS;
        int t = t0 - KT + r;
        if (t < 0) t = 0;
        slds[r * C + c] = csb[(size_t)c * CS_STRIDE + t];
    }
    const float* llp = ws + 128;
    for (int i = tid; i < KT * C; i += 256) sllp[i] = llp[i];
    if (tid < C) slncc[tid] = ws[tid];
    __syncthreads();

    const int c4 = (tid & 7) << 2;
    const int tb = tid >> 3;
    const int ja = tb + KT;
    const int jb = ja + 32;
    const int ta = t0 + tb;
    const int tbig = t0 + 32 + tb;

    const f32x4 ea = *(const f32x4*)&slds[(ja + 1) * C + c4];
    const f32x4 eb = *(const f32x4*)&slds[(jb + 1) * C + c4];
    const f32x4 lncc4 = *(const f32x4*)&slncc[c4];

    float* ob = out + ((size_t)(b * KT) * T + t0) * C + c4;

#pragma unroll
    for (int k = 0; k < KT; ++k) {
        const f32x4 lv = *(const f32x4*)&sllp[k * C + c4];
        const f32x4 sa = *(const f32x4*)&slds[(ja - k) * C + c4];
        const f32x4 sb = *(const f32x4*)&slds[(jb - k) * C + c4];
        const f32x4 mk = BIG_NEG - (float)(k + 1) * lncc4;
        f32x4 ra = ea - sa + lv;
        f32x4 rb = eb - sb + lv;
        if (ta < k) ra = mk + lv;
        if (tbig < k) rb = mk + lv;
        float* op = ob + (size_t)k * T * C;
        *(f32x4*)(op + tb * C) = ra;
        *(f32x4*)(op + (32 + tb) * C) = rb;
    }
}

// runtime-K fallback (dynamic LDS)
__global__ __launch_bounds__(256) void span_kernel_rt(
    const float* __restrict__ cs,
    const float* __restrict__ ws,
    float* __restrict__ out,
    int K)
{
    extern __shared__ float dyn[];
    float* slds = dyn;                  // (64+K+1)*C
    float* sllp = dyn + (64 + K + 1) * C;
    float* slncc = sllp + K * C;

    const int tid = threadIdx.x;
    const int b = blockIdx.x & 15;
    const int t0 = (blockIdx.x >> 4) << 6;
    const int ROWS = 64 + K + 1;

    const float* csb = cs + (size_t)b * C * CS_STRIDE;
    for (int i = tid; i < ROWS * C; i += 256) {
        const int c = i / ROWS;
        const int r = i - c * ROWS;
        int t = t0 - K + r;
        if (t < 0) t = 0;
        slds[r * C + c] = csb[(size_t)c * CS_STRIDE + t];
    }
    const float* llp = ws + 128;
    for (int i = tid; i < K * C; i += 256) sllp[i] = llp[i];
    if (tid < C) slncc[tid] = ws[tid];
    __syncthreads();

    const int c4 = (tid & 7) << 2;
    const int tb = tid >> 3;
    const int ja = tb + K;
    const int jb = ja + 32;
    const int ta = t0 + tb;
    const int tbig = t0 + 32 + tb;

    const f32x4 ea = *(const f32x4*)&slds[(ja + 1) * C + c4];
    const f32x4 eb = *(const f32x4*)&slds[(jb + 1) * C + c4];
    const f32x4 lncc4 = *(const f32x4*)&slncc[c4];

    float* ob = out + ((size_t)(b * K) * T + t0) * C + c4;

    for (int k = 0; k < K; ++k) {
        const f32x4 lv = *(const f32x4*)&sllp[k * C + c4];
        const f32x4 sa = *(const f32x4*)&slds[(ja - k) * C + c4];
        const f32x4 sb = *(const f32x4*)&slds[(jb - k) * C + c4];
        const f32x4 mk = BIG_NEG - (float)(k + 1) * lncc4;
        f32x4 ra = ea - sa + lv;
        f32x4 rb = eb - sb + lv;
        if (ta < k) ra = mk + lv;
        if (tbig < k) rb = mk + lv;
        float* op = ob + (size_t)k * T * C;
        *(f32x4*)(op + tb * C) = ra;
        *(f32x4*)(op + (32 + tb) * C) = rb;
    }
}

// ---------------------------------------------------------------------------
extern "C" void kernel_launch(void* const* d_in, const int* in_sizes, int n_in,
                              void* d_out, int out_size, void* d_ws, size_t ws_size,
                              hipStream_t stream) {
    const float* feat   = (const float*)d_in[0];
    const float* P      = (const float*)d_in[1];
    const float* TL     = (const float*)d_in[2];
    const float* TR     = (const float*)d_in[3];
    const float* MEANS  = (const float*)d_in[4];
    const float* STDV   = (const float*)d_in[5];
    const float* PLR    = (const float*)d_in[6];
    const float* LOGITS = (const float*)d_in[7];

    const int K = (out_size - (C * C + C)) / (B * T * C);

    float* ws  = (float*)d_ws;
    float* cs  = ws + 4096;
    float* emT = cs + (size_t)B * C * CS_STRIDE;

    float* out       = (float*)d_out;
    float* out_trans = out + (size_t)B * K * T * C;
    float* out_init  = out_trans + C * C;

    fused_kernel<<<514, 256, 0, stream>>>(feat, P, TL, TR, STDV, MEANS,
                                          PLR, LOGITS, ws, emT,
                                          out_trans, out_init, K);

    scan_kernel<<<B * C, 256, 0, stream>>>(emT, cs);

    const int nblk = B * (T / 64);     // 512 blocks: (b, 32 chunks)
    if (K == 20) {
        span_kernel_t<20><<<nblk, 256, 0, stream>>>(cs, ws, out);
    } else if (K == 16) {
        span_kernel_t<16><<<nblk, 256, 0, stream>>>(cs, ws, out);
    } else if (K == 24) {
        span_kernel_t<24><<<nblk, 256, 0, stream>>>(cs, ws, out);
    } else {
        const size_t smem = (size_t)((64 + K + 1) + K + 1) * C * sizeof(float);
        span_kernel_rt<<<nblk, 256, smem, stream>>>(cs, ws, out, K);
    }
}

// Round 12
// 29.484 us; speedup vs baseline: 2.2083x; 1.2505x over previous
//
#include <hip/hip_runtime.h>
#include <math.h>

#define BIG_NEG (-1.0e9f)

constexpr int B = 16, T = 2048, D = 64, C = 32, NF = 16;

typedef float f32x4 __attribute__((ext_vector_type(4)));

// ---------------------------------------------------------------------------
// megakernel: ONE launch does everything.
//  blocks 0..511 : (b, t-chunk of 64) -> stage feat halo tile, compute em
//                  locally, LOCAL sliding-window scan (global cumsum prefix
//                  cancels in cs[e]-cs[s]!), emit K contiguous output panels.
//  block  512    : transition log-softmax (C x C)
//  block  513    : init_lp
// em_core = xm - 0.5*xx; log_norm+cc folded into llp_eff; masked entries
// corrected by BIG_NEG - (k+1)*(ln+cc[c]).
// ---------------------------------------------------------------------------
template<int KT, bool EXACT>
__global__ __launch_bounds__(256) void megakernel(
    const float* __restrict__ feat,    // (B,T,D)
    const float* __restrict__ P,       // (D,NF)
    const float* __restrict__ TL,      // (C,D)
    const float* __restrict__ TR,      // (C,D)
    const float* __restrict__ STD,     // (D,)
    const float* __restrict__ MEANS,   // (C,D)
    const float* __restrict__ PLR,     // (C,)
    const float* __restrict__ LOGITS,  // (C,)
    float* __restrict__ out,           // (B,K,T,C)
    float* __restrict__ out_trans,     // (C,C)
    float* __restrict__ out_init,      // (C,)
    int Krt)
{
    constexpr int RTOT = 64 + KT;          // staged em rows (halo + chunk)
    constexpr int RPS  = (RTOT + 7) / 8;   // rows per scan-thread

    __shared__ float fs[RTOT * 64];        // feat tile (swizzled); later S[]
    __shared__ float wm_lds[C * 68];       // means*inv_var, padded stride
    __shared__ float iv_lds[64];
    __shared__ float E[RTOT * 33];         // em values [r][c], padded
    __shared__ float sllp[KT * C];         // llp_eff
    __shared__ float slncc[C];             // ln + cc[c]
    __shared__ float red[8 * 33];
    __shared__ float lgam[32];
    __shared__ float scc[C];
    __shared__ float sln;

    const int bid = blockIdx.x;
    const int tid = threadIdx.x;
    const int KRUN = EXACT ? KT : Krt;

    if (bid < 512) {
        const int b  = bid & 15;            // XCD = b%8
        const int t0 = (bid >> 4) << 6;

        // ---- stage feat rows [t0-KT, t0+64) into fs (XOR-swizzled) ----
        const float* fb = feat + (size_t)b * T * D;
        constexpr int NF4 = RTOT * 16;
#pragma unroll
        for (int it = 0; it < (NF4 + 255) / 256; ++it) {
            const int idx4 = tid + it * 256;
            if (idx4 < NF4) {
                const int fi  = idx4 * 4;
                const int row = fi >> 6;
                const int col = fi & 63;
                const int t   = t0 - KT + row;
                f32x4 v = {0.f, 0.f, 0.f, 0.f};
                if (t >= 0) v = *(const f32x4*)(fb + (size_t)t * D + col);
                const int cswz = col ^ (((row >> 2) & 7) << 2);
                *(f32x4*)(fs + row * 64 + cswz) = v;
            }
        }
        // ---- stage wm = MEANS * iv, and iv ----
#pragma unroll
        for (int it = 0; it < 2; ++it) {
            const int idx = tid * 4 + it * 1024;
            const int c = idx >> 6, d = idx & 63;
            const f32x4 m = *(const f32x4*)(MEANS + idx);
            const f32x4 s = *(const f32x4*)(STD + d);
            f32x4 w = {m.x / (s.x * s.x), m.y / (s.y * s.y),
                       m.z / (s.z * s.z), m.w / (s.w * s.w)};
            *(f32x4*)(wm_lds + c * 68 + d) = w;
        }
        if (tid < 16) {
            const f32x4 s = *(const f32x4*)(STD + tid * 4);
            f32x4 v = {1.f / (s.x * s.x), 1.f / (s.y * s.y),
                       1.f / (s.z * s.z), 1.f / (s.w * s.w)};
            *(f32x4*)(iv_lds + tid * 4) = v;
        }
        // ---- scalar tables: lgam (wave0), ln (wave1), cc (wave3) ----
        if (tid < 32) {
            float x = (tid >= 1) ? logf((float)(tid + 1)) : 0.f;
#pragma unroll
            for (int off = 1; off < 32; off <<= 1) {
                float vv = __shfl_up(x, off, 64);
                if (tid >= off) x += vv;
            }
            lgam[tid] = x;                 // lgamma(k+2) for k=tid
        } else if (tid >= 64 && tid < 128) {
            const int l = tid - 64;
            float lg = logf(STD[l]);
#pragma unroll
            for (int off = 1; off < 64; off <<= 1) lg += __shfl_xor(lg, off, 64);
            if (l == 0) sln = -lg - 58.81206612510332f;
        } else if (tid >= 192 && tid < 224) {
            const int c = tid - 192;
            float acc = 0.f;
#pragma unroll
            for (int dq = 0; dq < 64; dq += 4) {
                const f32x4 m = *(const f32x4*)(MEANS + c * 64 + dq);
                const f32x4 s = *(const f32x4*)(STD + dq);
                acc += (m.x * m.x) / (s.x * s.x) + (m.y * m.y) / (s.y * s.y)
                     + (m.z * m.z) / (s.z * s.z) + (m.w * m.w) / (s.w * s.w);
            }
            scc[c] = -0.5f * acc;
        }
        __syncthreads();

        // ---- emission into E: thread (i = t-quad, j = c-pair) ----
        const int j = tid >> 4;
        const float* wr0 = wm_lds + (2 * j) * 68;
        const float* wr1 = wr0 + 68;
#pragma unroll
        for (int pass = 0; pass < 2; ++pass) {
            const int i = (tid & 15) + pass * 16;
            if (pass == 0 || (tid & 15) < (KT / 4)) {
                const int swz = (i & 7) << 2;
                float a0[4] = {0,0,0,0}, a1[4] = {0,0,0,0}, xx[4] = {0,0,0,0};
#pragma unroll
                for (int q = 0; q < 16; ++q) {
                    const int dq = q * 4;
                    const f32x4 w0  = *(const f32x4*)(wr0 + dq);
                    const f32x4 w1  = *(const f32x4*)(wr1 + dq);
                    const f32x4 iv4 = *(const f32x4*)(iv_lds + dq);
                    const int cswz = dq ^ swz;
#pragma unroll
                    for (int tt = 0; tt < 4; ++tt) {
                        const f32x4 f = *(const f32x4*)(fs + (4*i+tt)*64 + cswz);
                        a0[tt] = fmaf(f.x, w0.x, a0[tt]); a0[tt] = fmaf(f.y, w0.y, a0[tt]);
                        a0[tt] = fmaf(f.z, w0.z, a0[tt]); a0[tt] = fmaf(f.w, w0.w, a0[tt]);
                        a1[tt] = fmaf(f.x, w1.x, a1[tt]); a1[tt] = fmaf(f.y, w1.y, a1[tt]);
                        a1[tt] = fmaf(f.z, w1.z, a1[tt]); a1[tt] = fmaf(f.w, w1.w, a1[tt]);
                        xx[tt] = fmaf(f.x * iv4.x, f.x, xx[tt]);
                        xx[tt] = fmaf(f.y * iv4.y, f.y, xx[tt]);
                        xx[tt] = fmaf(f.z * iv4.z, f.z, xx[tt]);
                        xx[tt] = fmaf(f.w * iv4.w, f.w, xx[tt]);
                    }
                }
#pragma unroll
                for (int tt = 0; tt < 4; ++tt) {
                    E[(4*i+tt) * 33 + 2*j]     = a0[tt] - 0.5f * xx[tt];
                    E[(4*i+tt) * 33 + 2*j + 1] = a1[tt] - 0.5f * xx[tt];
                }
            }
        }
        // ---- llp_eff + lncc (uses lgam/sln/scc staged before barrier) ----
        if (tid < C) slncc[tid] = sln + scc[tid];
        for (int e = tid; e < KRUN * C; e += 256) {
            const int k = e >> 5, c = e & 31;
            const float plr = PLR[c];
            sllp[e] = (float)(k + 1) * (plr + sln + scc[c]) - expf(plr) - lgam[k];
        }
        __syncthreads();

        // ---- LOCAL scan of E -> S in fs (prefix from t<t0-KT cancels) ----
        {
            const int c = tid & 31, s = tid >> 5;
            float incl[RPS];
            float run = 0.f;
#pragma unroll
            for (int q = 0; q < RPS; ++q) {
                const int r = s * RPS + q;
                const float v = (r < RTOT) ? E[r * 33 + c] : 0.f;
                run += v;
                incl[q] = run;
            }
            red[s * 33 + c] = run;
            __syncthreads();
            float off = 0.f;
#pragma unroll
            for (int s2 = 0; s2 < 7; ++s2) off += (s2 < s) ? red[s2 * 33 + c] : 0.f;
            float* slds = fs;                    // reuse (f no longer needed)
            if (s == 0) slds[c] = 0.f;           // S[0]
#pragma unroll
            for (int q = 0; q < RPS; ++q) {
                const int r = s * RPS + q;
                if (r < RTOT) slds[(r + 1) * 32 + c] = off + incl[q];
            }
        }
        __syncthreads();

        // ---- span compute + contiguous panel stores ----
        const float* slds = fs;
        const int c4 = (tid & 7) << 2;
        const int tb = tid >> 3;                 // 0..31
        const int ja = tb + KT;
        const int jb = ja + 32;
        const int ta = t0 + tb;
        const int tbg = t0 + 32 + tb;

        const f32x4 ea = *(const f32x4*)&slds[(ja + 1) * 32 + c4];
        const f32x4 eb = *(const f32x4*)&slds[(jb + 1) * 32 + c4];
        const f32x4 ln4 = *(const f32x4*)&slncc[c4];

        float* ob = out + ((size_t)(b * KRUN) * T + t0) * C + c4;
#pragma unroll
        for (int k = 0; k < KRUN; ++k) {         // fully unrolls when EXACT
            const f32x4 lv = *(const f32x4*)&sllp[k * 32 + c4];
            const f32x4 sa = *(const f32x4*)&slds[(ja - k) * 32 + c4];
            const f32x4 sb = *(const f32x4*)&slds[(jb - k) * 32 + c4];
            const f32x4 mk = BIG_NEG - (float)(k + 1) * ln4;
            f32x4 ra = ea - sa + lv;
            f32x4 rb = eb - sb + lv;
            if (ta < k) ra = mk + lv;
            if (tbg < k) rb = mk + lv;
            float* op = ob + (size_t)k * T * C;
            *(f32x4*)(op + tb * C) = ra;
            *(f32x4*)(op + (32 + tb) * C) = rb;
        }

    } else if (bid == 512) {
        // ---------------- transition log-softmax (reuses fs) ----------------
        float* left  = fs;            // C*NF
        float* right = fs + 512;      // C*NF
        float* M     = fs + 1024;     // C*(C+1)
        float* lse   = fs + 2112;     // C
        for (int e = tid; e < C * NF; e += 256) {
            int cc = e >> 4, f = e & (NF - 1);
            float aL = 0.f, aR = 0.f;
            for (int d = 0; d < D; ++d) {
                float p = P[d * NF + f];
                aL = fmaf(TL[cc * D + d], p, aL);
                aR = fmaf(TR[cc * D + d], p, aR);
            }
            left[cc * NF + f] = aL;
            right[cc * NF + f] = aR;
        }
        __syncthreads();
        for (int e = tid; e < C * C; e += 256) {
            int i = e >> 5, jj = e & 31;
            float acc = 0.f;
            for (int f = 0; f < NF; ++f)
                acc = fmaf(right[i * NF + f], left[jj * NF + f], acc);
            M[i * 33 + jj] = acc;
        }
        __syncthreads();
        if (tid < C) {
            float mx = -INFINITY;
            for (int i = 0; i < C; ++i) mx = fmaxf(mx, M[i * 33 + tid]);
            float s = 0.f;
            for (int i = 0; i < C; ++i) s += expf(M[i * 33 + tid] - mx);
            lse[tid] = logf(s) + mx;
        }
        __syncthreads();
        for (int e = tid; e < C * C; e += 256)
            out_trans[e] = M[(e >> 5) * 33 + (e & 31)] - lse[e & 31];

    } else {
        // ---------------- init_lp ----------------
        if (tid < 32) {
            float vv = LOGITS[tid];
            float mx = vv;
#pragma unroll
            for (int off = 1; off < 32; off <<= 1)
                mx = fmaxf(mx, __shfl_xor(mx, off, 64));
            float s = expf(vv - mx);
#pragma unroll
            for (int off = 1; off < 32; off <<= 1) s += __shfl_xor(s, off, 64);
            out_init[tid] = vv - mx - logf(s);
        }
    }
}

// ---------------------------------------------------------------------------
extern "C" void kernel_launch(void* const* d_in, const int* in_sizes, int n_in,
                              void* d_out, int out_size, void* d_ws, size_t ws_size,
                              hipStream_t stream) {
    const float* feat   = (const float*)d_in[0];
    const float* P      = (const float*)d_in[1];
    const float* TL     = (const float*)d_in[2];
    const float* TR     = (const float*)d_in[3];
    const float* MEANS  = (const float*)d_in[4];
    const float* STDV   = (const float*)d_in[5];
    const float* PLR    = (const float*)d_in[6];
    const float* LOGITS = (const float*)d_in[7];

    const int K = (out_size - (C * C + C)) / (B * T * C);

    float* out       = (float*)d_out;
    float* out_trans = out + (size_t)B * K * T * C;
    float* out_init  = out_trans + C * C;

    if (K == 20) {
        megakernel<20, true><<<514, 256, 0, stream>>>(
            feat, P, TL, TR, STDV, MEANS, PLR, LOGITS,
            out, out_trans, out_init, K);
    } else if (K == 16) {
        megakernel<16, true><<<514, 256, 0, stream>>>(
            feat, P, TL, TR, STDV, MEANS, PLR, LOGITS,
            out, out_trans, out_init, K);
    } else if (K == 24) {
        megakernel<24, true><<<514, 256, 0, stream>>>(
            feat, P, TL, TR, STDV, MEANS, PLR, LOGITS,
            out, out_trans, out_init, K);
    } else {
        megakernel<32, false><<<514, 256, 0, stream>>>(
            feat, P, TL, TR, STDV, MEANS, PLR, LOGITS,
            out, out_trans, out_init, K);
    }
}